// Round 1
// baseline (2267.053 us; speedup 1.0000x reference)
//
#include <hip/hip_runtime.h>
#include <math.h>

#define NPTS 500000
#define KH 129
#define PLANE (256*129)   // 33024

__device__ __forceinline__ int brev8(int n) { return (int)(__brev((unsigned)n) >> 24); }

// 256-point in-LDS radix-2 DIT FFT. 64 threads (one wave). buf holds
// bit-reversed-loaded data on entry. sign=-1 forward, +1 inverse (unscaled).
__device__ void fft256(float2* buf, int tid, float sign) {
    __syncthreads();
    #pragma unroll
    for (int len = 2; len <= 256; len <<= 1) {
        int half = len >> 1;
        float base = sign * 6.283185307179586f / (float)len;
        #pragma unroll
        for (int jj = 0; jj < 2; jj++) {
            int j = tid + jj * 64;
            int pos = j & (half - 1);
            int i0 = 2 * j - pos;          // = (j/half)*len + pos
            int i1 = i0 + half;
            float sn, cs;
            __sincosf(base * (float)pos, &sn, &cs);
            float2 u = buf[i0], v = buf[i1];
            float2 w = make_float2(v.x * cs - v.y * sn, v.x * sn + v.y * cs);
            buf[i0] = make_float2(u.x + w.x, u.y + w.y);
            buf[i1] = make_float2(u.x - w.x, u.y - w.y);
        }
        __syncthreads();
    }
}

// ---- rasterize: trilinear scatter-add of channel d of N into R[256^3] ----
__global__ void k_rasterize(const float* __restrict__ V, const float* __restrict__ N,
                            float* __restrict__ R, int d) {
    int i = blockIdx.x * blockDim.x + threadIdx.x;
    if (i >= NPTS) return;
    float xs = V[3 * i + 0] * 256.0f;
    float ys = V[3 * i + 1] * 256.0f;
    float zs = V[3 * i + 2] * 256.0f;
    float val = N[3 * i + d];
    int ix0 = (int)floorf(xs), iy0 = (int)floorf(ys), iz0 = (int)floorf(zs);
    float fx = xs - (float)ix0, fy = ys - (float)iy0, fz = zs - (float)iz0;
    int ix1 = (ix0 + 1) & 255, iy1 = (iy0 + 1) & 255, iz1 = (iz0 + 1) & 255;
    #pragma unroll
    for (int c = 0; c < 8; c++) {
        int bx = (c >> 2) & 1, by = (c >> 1) & 1, bz = c & 1;
        int ix = bx ? ix1 : ix0, iy = by ? iy1 : iy0, iz = bz ? iz1 : iz0;
        float w = (bx ? fx : 1.0f - fx) * (by ? fy : 1.0f - fy) * (bz ? fz : 1.0f - fz);
        atomicAdd(&R[(((size_t)ix << 8) + (size_t)iy) * 256 + (size_t)iz], w * val);
    }
}

// ---- forward rfft along z (contiguous). One block per (x,y) line. ----
__global__ void k_rfft_z(const float* __restrict__ R, float2* __restrict__ C) {
    __shared__ float2 buf[256];
    int x = blockIdx.x, y = blockIdx.y, tid = threadIdx.x;
    const float* src = R + ((size_t)x * 256 + (size_t)y) * 256;
    #pragma unroll
    for (int c = 0; c < 4; c++) {
        int n = tid + 64 * c;
        buf[brev8(n)] = make_float2(src[n], 0.0f);
    }
    fft256(buf, tid, -1.0f);
    float2* dst = C + ((size_t)x * 256 + (size_t)y) * KH;
    dst[tid] = buf[tid];
    dst[tid + 64] = buf[tid + 64];
    if (tid == 0) dst[128] = buf[128];
}

// ---- complex FFT along y (stride KH). In place. One block per (x,k). ----
__global__ void k_fft_y(float2* __restrict__ C, float sign) {
    __shared__ float2 buf[256];
    int x = blockIdx.x, k = blockIdx.y, tid = threadIdx.x;
    float2* base = C + (size_t)x * PLANE + (size_t)k;
    #pragma unroll
    for (int c = 0; c < 4; c++) {
        int n = tid + 64 * c;
        buf[brev8(n)] = base[(size_t)n * KH];
    }
    fft256(buf, tid, sign);
    #pragma unroll
    for (int c = 0; c < 4; c++) {
        int n = tid + 64 * c;
        base[(size_t)n * KH] = buf[n];
    }
}

// ---- forward FFT along x (stride PLANE) fused with spectral MAC into Acc ----
__global__ void k_fft_x_accum(const float2* __restrict__ C, float2* __restrict__ Acc, int d) {
    __shared__ float2 buf[256];
    int y = blockIdx.x, k = blockIdx.y, tid = threadIdx.x;
    const float2* base = C + (size_t)y * KH + (size_t)k;
    #pragma unroll
    for (int c = 0; c < 4; c++) {
        int n = tid + 64 * c;
        buf[brev8(n)] = base[(size_t)n * PLANE];
    }
    fft256(buf, tid, -1.0f);
    float2* abase = Acc + (size_t)y * KH + (size_t)k;
    float fy = (y < 128) ? (float)y : (float)(y - 256);
    float fz = (float)k;
    #pragma unroll
    for (int c = 0; c < 4; c++) {
        int n = tid + 64 * c;
        float fx = (n < 128) ? (float)n : (float)(n - 256);
        float f2 = fx * fx + fy * fy + fz * fz;
        float G = __expf(-0.0030517578125f * f2);         // exp(-0.5*(2*SIG*|f|/256)^2), SIG=10
        float fd = (d == 0) ? fx : ((d == 1) ? fy : fz);
        float omd = 6.283185307179586f * fd;              // 2*pi*f_d
        float lap = 1e-6f - 39.47841760435743f * f2;      // Lap + 1e-6, Lap = -4*pi^2*|f|^2
        float s = G * omd / lap;
        float2 v = buf[n];
        // (-i * s) * v = (s*v.y, -s*v.x)
        size_t idx = (size_t)n * PLANE;
        float2 old = abase[idx];
        abase[idx] = make_float2(old.x + s * v.y, old.y - s * v.x);
    }
}

// ---- inverse complex FFT along x (stride PLANE). In place. ----
__global__ void k_fft_x(float2* __restrict__ A, float sign) {
    __shared__ float2 buf[256];
    int y = blockIdx.x, k = blockIdx.y, tid = threadIdx.x;
    float2* base = A + (size_t)y * KH + (size_t)k;
    #pragma unroll
    for (int c = 0; c < 4; c++) {
        int n = tid + 64 * c;
        buf[brev8(n)] = base[(size_t)n * PLANE];
    }
    fft256(buf, tid, sign);
    #pragma unroll
    for (int c = 0; c < 4; c++) {
        int n = tid + 64 * c;
        base[(size_t)n * PLANE] = buf[n];
    }
}

// ---- inverse rfft along z with Hermitian extension; total 1/256^3 scale ----
__global__ void k_irfft_z(const float2* __restrict__ A, float* __restrict__ out) {
    __shared__ float2 buf[256];
    int x = blockIdx.x, y = blockIdx.y, tid = threadIdx.x;
    const float2* src = A + ((size_t)x * 256 + (size_t)y) * KH;
    #pragma unroll
    for (int c = 0; c < 4; c++) {
        int n = tid + 64 * c;
        float2 v;
        if (n <= 128) v = src[n];
        else { v = src[256 - n]; v.y = -v.y; }
        buf[brev8(n)] = v;
    }
    fft256(buf, tid, 1.0f);
    float* dst = out + ((size_t)x * 256 + (size_t)y) * 256;
    const float scale = 1.0f / 16777216.0f;
    #pragma unroll
    for (int c = 0; c < 4; c++) {
        int n = tid + 64 * c;
        dst[n] = buf[n].x * scale;
    }
}

// ---- trilinear interp of phi at points, sum-reduce into S ----
__global__ void k_interp_sum(const float* __restrict__ phi, const float* __restrict__ V,
                             float* __restrict__ S) {
    int i = blockIdx.x * blockDim.x + threadIdx.x;
    float acc = 0.0f;
    if (i < NPTS) {
        float xs = V[3 * i + 0] * 256.0f;
        float ys = V[3 * i + 1] * 256.0f;
        float zs = V[3 * i + 2] * 256.0f;
        int ix0 = (int)floorf(xs), iy0 = (int)floorf(ys), iz0 = (int)floorf(zs);
        float fx = xs - (float)ix0, fy = ys - (float)iy0, fz = zs - (float)iz0;
        int ix1 = (ix0 + 1) & 255, iy1 = (iy0 + 1) & 255, iz1 = (iz0 + 1) & 255;
        #pragma unroll
        for (int c = 0; c < 8; c++) {
            int bx = (c >> 2) & 1, by = (c >> 1) & 1, bz = c & 1;
            int ix = bx ? ix1 : ix0, iy = by ? iy1 : iy0, iz = bz ? iz1 : iz0;
            float w = (bx ? fx : 1.0f - fx) * (by ? fy : 1.0f - fy) * (bz ? fz : 1.0f - fz);
            acc += w * phi[(((size_t)ix << 8) + (size_t)iy) * 256 + (size_t)iz];
        }
    }
    #pragma unroll
    for (int off = 32; off > 0; off >>= 1) acc += __shfl_down(acc, off, 64);
    if ((threadIdx.x & 63) == 0) atomicAdd(S, acc);
}

// sc_out[0] = mean, sc_out[1] = 0.5/|phi[0]-mean|
__global__ void k_scalars(const float* __restrict__ S, const float* __restrict__ phi,
                          float* __restrict__ sc_out) {
    float mean = S[0] * (1.0f / (float)NPTS);
    sc_out[0] = mean;
    sc_out[1] = 0.5f / fabsf(phi[0] - mean);
}

// out = -(out - mean) * inv   (vectorized float4, exact grid: 16777216/4 elems)
__global__ void k_scale(float* __restrict__ phi, const float* __restrict__ sc) {
    size_t i = (size_t)blockIdx.x * blockDim.x + threadIdx.x;
    float mean = sc[0], inv = sc[1];
    float4* p = (float4*)phi;
    float4 v = p[i];
    v.x = -(v.x - mean) * inv;
    v.y = -(v.y - mean) * inv;
    v.z = -(v.z - mean) * inv;
    v.w = -(v.w - mean) * inv;
    p[i] = v;
}

extern "C" void kernel_launch(void* const* d_in, const int* in_sizes, int n_in,
                              void* d_out, int out_size, void* d_ws, size_t ws_size,
                              hipStream_t stream) {
    const float* V = (const float*)d_in[0];
    const float* N = (const float*)d_in[1];
    float* out = (float*)d_out;

    const size_t R_BYTES = 256ull * 256 * 256 * 4;        // 67108864
    const size_t C_BYTES = 256ull * 256 * KH * 8;         // 67633152
    const size_t NEEDED = R_BYTES + 2 * C_BYTES + 64;
    if (ws_size < NEEDED) return;  // fail cleanly instead of corrupting memory

    char* ws = (char*)d_ws;
    float*  R   = (float*)ws;
    float2* C   = (float2*)(ws + R_BYTES);
    float2* Acc = (float2*)(ws + R_BYTES + C_BYTES);
    float*  sc  = (float*)(ws + R_BYTES + 2 * C_BYTES);   // [0]=S, [1]=mean, [2]=inv

    hipMemsetAsync(Acc, 0, C_BYTES, stream);
    hipMemsetAsync(sc, 0, 16, stream);

    dim3 b64(64);
    dim3 g_xy(256, 256);   // (x,y) lines for z-axis transforms
    dim3 g_xk(256, KH);    // (x,k) lines for y-axis transforms
    dim3 g_yk(256, KH);    // (y,k) lines for x-axis transforms

    for (int d = 0; d < 3; d++) {
        hipMemsetAsync(R, 0, R_BYTES, stream);
        k_rasterize<<<(NPTS + 255) / 256, 256, 0, stream>>>(V, N, R, d);
        k_rfft_z<<<g_xy, b64, 0, stream>>>(R, C);
        k_fft_y<<<g_xk, b64, 0, stream>>>(C, -1.0f);
        k_fft_x_accum<<<g_yk, b64, 0, stream>>>(C, Acc, d);
    }

    k_fft_x<<<g_yk, b64, 0, stream>>>(Acc, 1.0f);
    k_fft_y<<<g_xk, b64, 0, stream>>>(Acc, 1.0f);
    k_irfft_z<<<g_xy, b64, 0, stream>>>(Acc, out);

    k_interp_sum<<<(NPTS + 255) / 256, 256, 0, stream>>>(out, V, sc);
    k_scalars<<<1, 1, 0, stream>>>(sc, out, sc + 1);
    k_scale<<<16777216 / 4 / 256, 256, 0, stream>>>(out, sc + 1);
}

// Round 2
// 1385.379 us; speedup vs baseline: 1.6364x; 1.6364x over previous
//
#include <hip/hip_runtime.h>
#include <math.h>

#define NPTS 500000
#define KH 129

// base-4 digit reversal of 8-bit index (involution)
__device__ __forceinline__ int rev4(int n) {
    return ((n & 3) << 6) | ((n & 12) << 2) | ((n & 48) >> 2) | ((n & 192) >> 6);
}

__device__ __forceinline__ void cmul(float ar, float ai, float br, float bi,
                                     float& cr, float& ci) {
    cr = ar * br - ai * bi;
    ci = ar * bi + ai * br;
}

// 16 independent 256-pt radix-4 DIT FFTs in LDS (SoA, line stride 257 floats).
// 256 threads: thread t works on line t>>4 with lane t&15.
// Input must be stored digit-reversed (rev4); output natural. Unnormalized.
// sign = -1 forward, +1 inverse.
__device__ void fft256x16(float* RE, float* IM, int tid, float sign) {
    const int line = tid >> 4, lane = tid & 15;
    float* re = RE + line * 257;
    float* im = IM + line * 257;
    __syncthreads();
    #pragma unroll
    for (int st = 0; st < 4; st++) {
        const int q = 1 << (2 * st);           // 1,4,16,64
        const float base = sign * 6.283185307179586f / (float)(q << 2);
        #pragma unroll
        for (int jj = 0; jj < 4; jj++) {
            const int j = lane + (jj << 4);    // 0..63
            const int pos = j & (q - 1);
            const int i0 = ((j >> (2 * st)) << (2 * st + 2)) + pos;
            const int i1 = i0 + q, i2 = i1 + q, i3 = i2 + q;
            float w1i, w1r;
            __sincosf(base * (float)pos, &w1i, &w1r);
            float w2r, w2i; cmul(w1r, w1i, w1r, w1i, w2r, w2i);
            float w3r, w3i; cmul(w2r, w2i, w1r, w1i, w3r, w3i);
            float ar = re[i0], ai = im[i0];
            float b0r = re[i1], b0i = im[i1];
            float c0r = re[i2], c0i = im[i2];
            float d0r = re[i3], d0i = im[i3];
            float br, bi; cmul(b0r, b0i, w1r, w1i, br, bi);
            float cr, ci; cmul(c0r, c0i, w2r, w2i, cr, ci);
            float dr, di; cmul(d0r, d0i, w3r, w3i, dr, di);
            float er = ar + cr, ei = ai + ci;
            float fr = ar - cr, fi = ai - ci;
            float gr = br + dr, gi = bi + di;
            float hr = br - dr, hi_ = bi - di;
            float sir = -sign * hi_, sii = sign * hr;   // sign*i*(b-d)
            re[i0] = er + gr;  im[i0] = ei + gi;
            re[i1] = fr + sir; im[i1] = fi + sii;
            re[i2] = er - gr;  im[i2] = ei - gi;
            re[i3] = fr - sir; im[i3] = fi - sii;
        }
        __syncthreads();
    }
}

// ---- rasterize: trilinear scatter-add of channel d of N into R[256^3] ----
__global__ void k_rasterize(const float* __restrict__ V, const float* __restrict__ N,
                            float* __restrict__ R, int d) {
    int i = blockIdx.x * blockDim.x + threadIdx.x;
    if (i >= NPTS) return;
    float xs = V[3 * i + 0] * 256.0f;
    float ys = V[3 * i + 1] * 256.0f;
    float zs = V[3 * i + 2] * 256.0f;
    float val = N[3 * i + d];
    int ix0 = (int)floorf(xs), iy0 = (int)floorf(ys), iz0 = (int)floorf(zs);
    float fx = xs - (float)ix0, fy = ys - (float)iy0, fz = zs - (float)iz0;
    int ix1 = (ix0 + 1) & 255, iy1 = (iy0 + 1) & 255, iz1 = (iz0 + 1) & 255;
    #pragma unroll
    for (int c = 0; c < 8; c++) {
        int bx = (c >> 2) & 1, by = (c >> 1) & 1, bz = c & 1;
        int ix = bx ? ix1 : ix0, iy = by ? iy1 : iy0, iz = bz ? iz1 : iz0;
        float w = (bx ? fx : 1.0f - fx) * (by ? fy : 1.0f - fy) * (bz ? fz : 1.0f - fz);
        atomicAdd(&R[(((size_t)ix << 8) + (size_t)iy) * 256 + (size_t)iz], w * val);
    }
}

// ---- forward rfft along z. Block: 16 (x,y)-lines. C layout [x][y][k], row khp ----
__global__ void k_rfft_z(const float* __restrict__ R, float2* __restrict__ C, int khp) {
    __shared__ float RE[16 * 257];
    __shared__ float IM[16 * 257];
    int x = blockIdx.x, y0 = blockIdx.y * 16, tid = threadIdx.x;
    #pragma unroll
    for (int l = 0; l < 16; l++) {
        float v = R[(((size_t)x << 8) + (y0 + l)) * 256 + tid];
        RE[l * 257 + rev4(tid)] = v;
        IM[l * 257 + rev4(tid)] = 0.0f;
    }
    fft256x16(RE, IM, tid, -1.0f);
    #pragma unroll
    for (int l = 0; l < 16; l++) {
        if (tid < KH) {
            C[(((size_t)x << 8) + (y0 + l)) * khp + tid] =
                make_float2(RE[l * 257 + tid], IM[l * 257 + tid]);
        }
    }
}

// ---- complex FFT along y, in place. Block: 16 k-columns at fixed x. ----
__global__ void k_fft_y(float2* __restrict__ C, int khp, float sign) {
    __shared__ float RE[16 * 257];
    __shared__ float IM[16 * 257];
    int x = blockIdx.x, k0 = blockIdx.y * 16, tid = threadIdx.x;
    int kl = tid & 15, k = k0 + kl;
    bool valid = (k < KH);
    float2* base = C + (size_t)x * 256 * khp + k;
    #pragma unroll
    for (int it = 0; it < 16; it++) {
        int y = (tid >> 4) + it * 16;
        float2 v = valid ? base[(size_t)y * khp] : make_float2(0.0f, 0.0f);
        RE[kl * 257 + rev4(y)] = v.x;
        IM[kl * 257 + rev4(y)] = v.y;
    }
    fft256x16(RE, IM, tid, sign);
    #pragma unroll
    for (int it = 0; it < 16; it++) {
        int y = (tid >> 4) + it * 16;
        if (valid) base[(size_t)y * khp] = make_float2(RE[kl * 257 + y], IM[kl * 257 + y]);
    }
}

// ---- forward FFT along x + spectral MAC into Acc; mode2 fuses inverse-x ----
// mode: 0 = write Acc, 1 = Acc += , 2 = Acc += ; then inverse-x FFT of Acc in place
__global__ void k_fft_x_acc(const float2* __restrict__ C, float2* __restrict__ Acc,
                            int khp, int mode, int d) {
    __shared__ float RE[16 * 257];
    __shared__ float IM[16 * 257];
    int y = blockIdx.x, k0 = blockIdx.y * 16, tid = threadIdx.x;
    int kl = tid & 15, k = k0 + kl;
    bool valid = (k < KH);
    size_t plane = (size_t)256 * khp;
    const float2* base = C + (size_t)y * khp + k;
    #pragma unroll
    for (int it = 0; it < 16; it++) {
        int n = (tid >> 4) + it * 16;
        float2 v = valid ? base[(size_t)n * plane] : make_float2(0.0f, 0.0f);
        RE[kl * 257 + rev4(n)] = v.x;
        IM[kl * 257 + rev4(n)] = v.y;
    }
    fft256x16(RE, IM, tid, -1.0f);
    float2* abase = Acc + (size_t)y * khp + k;
    float fy = (y < 128) ? (float)y : (float)(y - 256);
    float fz = (float)k;
    float vr[16], vi[16];
    #pragma unroll
    for (int it = 0; it < 16; it++) {
        int n = (tid >> 4) + it * 16;
        float fx = (n < 128) ? (float)n : (float)(n - 256);
        float f2 = fx * fx + fy * fy + fz * fz;
        float G = __expf(-0.0030517578125f * f2);          // exp(-0.5*(2*SIG*|f|/256)^2)
        float fd = (d == 0) ? fx : ((d == 1) ? fy : fz);
        float s = G * (6.283185307179586f * fd) / (1e-6f - 39.47841760435743f * f2);
        float xr = RE[kl * 257 + n], xi = IM[kl * 257 + n];
        float cr = s * xi, ci = -s * xr;                   // (-i*s)*v
        if (mode >= 1) {
            float2 old = valid ? abase[(size_t)n * plane] : make_float2(0.0f, 0.0f);
            cr += old.x; ci += old.y;
        }
        if (mode == 2) { vr[it] = cr; vi[it] = ci; }
        else if (valid) abase[(size_t)n * plane] = make_float2(cr, ci);
    }
    if (mode == 2) {
        __syncthreads();   // all reads of forward result done before overwrite
        #pragma unroll
        for (int it = 0; it < 16; it++) {
            int n = (tid >> 4) + it * 16;
            RE[kl * 257 + rev4(n)] = vr[it];
            IM[kl * 257 + rev4(n)] = vi[it];
        }
        fft256x16(RE, IM, tid, 1.0f);
        #pragma unroll
        for (int it = 0; it < 16; it++) {
            int n = (tid >> 4) + it * 16;
            if (valid) abase[(size_t)n * plane] =
                make_float2(RE[kl * 257 + n], IM[kl * 257 + n]);
        }
    }
}

// ---- inverse rfft along z with Hermitian extension; 1/256^3 scale ----
__global__ void k_irfft_z(const float2* __restrict__ A, float* __restrict__ out, int khp) {
    __shared__ float RE[16 * 257];
    __shared__ float IM[16 * 257];
    int x = blockIdx.x, y0 = blockIdx.y * 16, tid = threadIdx.x;
    #pragma unroll
    for (int l = 0; l < 16; l++) {
        const float2* src = A + (((size_t)x << 8) + (y0 + l)) * khp;
        int n = tid;
        int k = (n <= 128) ? n : 256 - n;
        float2 v = src[k];
        RE[l * 257 + rev4(n)] = v.x;
        IM[l * 257 + rev4(n)] = (n <= 128) ? v.y : -v.y;
    }
    fft256x16(RE, IM, tid, 1.0f);
    const float sc = 1.0f / 16777216.0f;
    #pragma unroll
    for (int l = 0; l < 16; l++) {
        out[(((size_t)x << 8) + (y0 + l)) * 256 + tid] = RE[l * 257 + tid] * sc;
    }
}

// ---- trilinear interp of phi at points, sum-reduce into S ----
__global__ void k_interp_sum(const float* __restrict__ phi, const float* __restrict__ V,
                             float* __restrict__ S) {
    int i = blockIdx.x * blockDim.x + threadIdx.x;
    float acc = 0.0f;
    if (i < NPTS) {
        float xs = V[3 * i + 0] * 256.0f;
        float ys = V[3 * i + 1] * 256.0f;
        float zs = V[3 * i + 2] * 256.0f;
        int ix0 = (int)floorf(xs), iy0 = (int)floorf(ys), iz0 = (int)floorf(zs);
        float fx = xs - (float)ix0, fy = ys - (float)iy0, fz = zs - (float)iz0;
        int ix1 = (ix0 + 1) & 255, iy1 = (iy0 + 1) & 255, iz1 = (iz0 + 1) & 255;
        #pragma unroll
        for (int c = 0; c < 8; c++) {
            int bx = (c >> 2) & 1, by = (c >> 1) & 1, bz = c & 1;
            int ix = bx ? ix1 : ix0, iy = by ? iy1 : iy0, iz = bz ? iz1 : iz0;
            float w = (bx ? fx : 1.0f - fx) * (by ? fy : 1.0f - fy) * (bz ? fz : 1.0f - fz);
            acc += w * phi[(((size_t)ix << 8) + (size_t)iy) * 256 + (size_t)iz];
        }
    }
    #pragma unroll
    for (int off = 32; off > 0; off >>= 1) acc += __shfl_down(acc, off, 64);
    if ((threadIdx.x & 63) == 0) atomicAdd(S, acc);
}

__global__ void k_scalars(const float* __restrict__ S, const float* __restrict__ phi,
                          float* __restrict__ sc_out) {
    float mean = S[0] * (1.0f / (float)NPTS);
    sc_out[0] = mean;
    sc_out[1] = 0.5f / fabsf(phi[0] - mean);
}

__global__ void k_scale(float* __restrict__ phi, const float* __restrict__ sc) {
    size_t i = (size_t)blockIdx.x * blockDim.x + threadIdx.x;
    float mean = sc[0], inv = sc[1];
    float4* p = (float4*)phi;
    float4 v = p[i];
    v.x = -(v.x - mean) * inv;
    v.y = -(v.y - mean) * inv;
    v.z = -(v.z - mean) * inv;
    v.w = -(v.w - mean) * inv;
    p[i] = v;
}

extern "C" void kernel_launch(void* const* d_in, const int* in_sizes, int n_in,
                              void* d_out, int out_size, void* d_ws, size_t ws_size,
                              hipStream_t stream) {
    const float* V = (const float*)d_in[0];
    const float* N = (const float*)d_in[1];
    float* out = (float*)d_out;

    const size_t R_BYTES = 256ull * 256 * 256 * 4;            // 64 MiB
    const size_t C129 = 256ull * 256 * 129 * 8;               // 67,633,152
    const size_t C144 = 256ull * 256 * 144 * 8;               // 75,497,472 (aligned rows)

    int khp; size_t cbytes;
    if (ws_size >= R_BYTES + 2 * C144 + 256)      { khp = 144; cbytes = C144; }
    else if (ws_size >= R_BYTES + 2 * C129 + 256) { khp = 129; cbytes = C129; }
    else return;

    char* ws = (char*)d_ws;
    float*  R   = (float*)ws;
    float2* C   = (float2*)(ws + R_BYTES);
    float2* Acc = (float2*)(ws + R_BYTES + cbytes);
    float*  sc  = (float*)(ws + R_BYTES + 2 * cbytes);        // [0]=S, [1]=mean, [2]=inv

    hipMemsetAsync(sc, 0, 16, stream);

    dim3 b256(256);
    dim3 g_z(256, 16);    // 16-line tiles of (x, y0..y0+15)
    dim3 g_t(256, 9);     // 16-k tiles (9 tiles cover 129/144)

    for (int d = 0; d < 3; d++) {
        hipMemsetAsync(R, 0, R_BYTES, stream);
        k_rasterize<<<(NPTS + 255) / 256, 256, 0, stream>>>(V, N, R, d);
        k_rfft_z<<<g_z, b256, 0, stream>>>(R, C, khp);
        k_fft_y<<<g_t, b256, 0, stream>>>(C, khp, -1.0f);
        k_fft_x_acc<<<g_t, b256, 0, stream>>>(C, Acc, khp, d, d);  // mode = d (0,1,2)
    }

    k_fft_y<<<g_t, b256, 0, stream>>>(Acc, khp, 1.0f);    // inverse y
    k_irfft_z<<<g_z, b256, 0, stream>>>(Acc, out, khp);   // inverse z + scale

    k_interp_sum<<<(NPTS + 255) / 256, 256, 0, stream>>>(out, V, sc);
    k_scalars<<<1, 1, 0, stream>>>(sc, out, sc + 1);
    k_scale<<<16777216 / 4 / 256, 256, 0, stream>>>(out, sc + 1);
}

// Round 3
// 1110.592 us; speedup vs baseline: 2.0413x; 1.2474x over previous
//
#include <hip/hip_runtime.h>
#include <math.h>

#define NPTS 500000
#define KH 129

// sort cells: 8x8x16 voxels -> 32x32x16 = 16384 cells, ~30.5 pts/cell
#define NKEY 16384

// base-4 digit reversal of 8-bit index (involution)
__device__ __forceinline__ int rev4(int n) {
    return ((n & 3) << 6) | ((n & 12) << 2) | ((n & 48) >> 2) | ((n & 192) >> 6);
}

__device__ __forceinline__ void cmul(float ar, float ai, float br, float bi,
                                     float& cr, float& ci) {
    cr = ar * br - ai * bi;
    ci = ar * bi + ai * br;
}

// 16 independent 256-pt radix-4 DIT FFTs in LDS (SoA, line stride 257 floats).
__device__ void fft256x16(float* RE, float* IM, int tid, float sign) {
    const int line = tid >> 4, lane = tid & 15;
    float* re = RE + line * 257;
    float* im = IM + line * 257;
    __syncthreads();
    #pragma unroll
    for (int st = 0; st < 4; st++) {
        const int q = 1 << (2 * st);           // 1,4,16,64
        const float base = sign * 6.283185307179586f / (float)(q << 2);
        #pragma unroll
        for (int jj = 0; jj < 4; jj++) {
            const int j = lane + (jj << 4);    // 0..63
            const int pos = j & (q - 1);
            const int i0 = ((j >> (2 * st)) << (2 * st + 2)) + pos;
            const int i1 = i0 + q, i2 = i1 + q, i3 = i2 + q;
            float w1i, w1r;
            __sincosf(base * (float)pos, &w1i, &w1r);
            float w2r, w2i; cmul(w1r, w1i, w1r, w1i, w2r, w2i);
            float w3r, w3i; cmul(w2r, w2i, w1r, w1i, w3r, w3i);
            float ar = re[i0], ai = im[i0];
            float b0r = re[i1], b0i = im[i1];
            float c0r = re[i2], c0i = im[i2];
            float d0r = re[i3], d0i = im[i3];
            float br, bi; cmul(b0r, b0i, w1r, w1i, br, bi);
            float cr, ci; cmul(c0r, c0i, w2r, w2i, cr, ci);
            float dr, di; cmul(d0r, d0i, w3r, w3i, dr, di);
            float er = ar + cr, ei = ai + ci;
            float fr = ar - cr, fi = ai - ci;
            float gr = br + dr, gi = bi + di;
            float hr = br - dr, hi_ = bi - di;
            float sir = -sign * hi_, sii = sign * hr;   // sign*i*(b-d)
            re[i0] = er + gr;  im[i0] = ei + gi;
            re[i1] = fr + sir; im[i1] = fi + sii;
            re[i2] = er - gr;  im[i2] = ei - gi;
            re[i3] = fr - sir; im[i3] = fi - sii;
        }
        __syncthreads();
    }
}

__device__ __forceinline__ int cell_key(float x, float y, float z) {
    int ix = (int)(x * 256.0f), iy = (int)(y * 256.0f), iz = (int)(z * 256.0f);
    return ((ix >> 3) << 9) | ((iy >> 3) << 4) | (iz >> 4);
}

// ---- sort pass 1: histogram of cell keys ----
__global__ void k_hist(const float* __restrict__ V, int* __restrict__ cnt) {
    int i = blockIdx.x * blockDim.x + threadIdx.x;
    if (i >= NPTS) return;
    atomicAdd(&cnt[cell_key(V[3 * i], V[3 * i + 1], V[3 * i + 2])], 1);
}

// ---- sort pass 2: exclusive scan of 16384 counts (single block) ----
__global__ void k_scan(const int* __restrict__ cnt, int* __restrict__ off,
                       int* __restrict__ cnt2) {
    __shared__ int s[256];
    int t = threadIdx.x;
    int sum = 0;
    for (int j = 0; j < 64; j++) sum += cnt[t * 64 + j];
    s[t] = sum;
    __syncthreads();
    if (t == 0) { int run = 0; for (int j = 0; j < 256; j++) { int c = s[j]; s[j] = run; run += c; } }
    __syncthreads();
    int run = s[t];
    for (int j = 0; j < 64; j++) {
        int c = cnt[t * 64 + j];
        off[t * 64 + j] = run;
        cnt2[t * 64 + j] = run;
        run += c;
    }
    if (t == 255) off[NKEY] = run;   // == NPTS
}

// ---- sort pass 3: scatter point indices into cell order ----
__global__ void k_scatter(const float* __restrict__ V, int* __restrict__ cnt2,
                          int* __restrict__ idx) {
    int i = blockIdx.x * blockDim.x + threadIdx.x;
    if (i >= NPTS) return;
    int s = atomicAdd(&cnt2[cell_key(V[3 * i], V[3 * i + 1], V[3 * i + 2])], 1);
    idx[s] = i;
}

// ---- atomic-free rasterize: one block owns an 8x8x16 voxel tile ----
// grid (16,32,32): blockIdx.x=cz, y=cy, z=cx
__global__ void k_rastg(const int* __restrict__ idx, const int* __restrict__ off,
                        const float* __restrict__ V, const float* __restrict__ N,
                        float* __restrict__ R, int d) {
    __shared__ float tile[1024];
    int t = threadIdx.x;
    #pragma unroll
    for (int q = 0; q < 4; q++) tile[t + q * 256] = 0.0f;
    __syncthreads();
    int CZ = blockIdx.x, CY = blockIdx.y, CX = blockIdx.z;
    int X0 = CX << 3, Y0 = CY << 3, Z0 = CZ << 4;
    #pragma unroll
    for (int cc = 0; cc < 8; cc++) {
        int cx = (CX - ((cc >> 2) & 1)) & 31;
        int cy = (CY - ((cc >> 1) & 1)) & 31;
        int cz = (CZ - (cc & 1)) & 15;
        int key = (cx << 9) | (cy << 4) | cz;
        int s = off[key], e = off[key + 1];
        for (int p = s + t; p < e; p += 256) {
            int i = idx[p];
            float xs = V[3 * i] * 256.0f, ys = V[3 * i + 1] * 256.0f, zs = V[3 * i + 2] * 256.0f;
            float val = N[3 * i + d];
            int ix0 = (int)xs, iy0 = (int)ys, iz0 = (int)zs;
            float fx = xs - ix0, fy = ys - iy0, fz = zs - iz0;
            #pragma unroll
            for (int c = 0; c < 8; c++) {
                int bx = (c >> 2) & 1, by = (c >> 1) & 1, bz = c & 1;
                int lx = ((bx ? ix0 + 1 : ix0) - X0) & 255;
                int ly = ((by ? iy0 + 1 : iy0) - Y0) & 255;
                int lz = ((bz ? iz0 + 1 : iz0) - Z0) & 255;
                if (lx < 8 && ly < 8 && lz < 16) {
                    float w = (bx ? fx : 1.0f - fx) * (by ? fy : 1.0f - fy) * (bz ? fz : 1.0f - fz);
                    atomicAdd(&tile[(((lx << 3) + ly) << 4) + lz], w * val);
                }
            }
        }
    }
    __syncthreads();
    #pragma unroll
    for (int q = 0; q < 4; q++) {
        int l = t + q * 256;
        int lx = l >> 7, ly = (l >> 4) & 7, lz = l & 15;
        R[(size_t)(((X0 + lx) << 16) | ((Y0 + ly) << 8) | (Z0 + lz))] = tile[l];
    }
}

// ---- fallback scatter-atomic rasterize (used if ws too small for sort) ----
__global__ void k_rasterize(const float* __restrict__ V, const float* __restrict__ N,
                            float* __restrict__ R, int d) {
    int i = blockIdx.x * blockDim.x + threadIdx.x;
    if (i >= NPTS) return;
    float xs = V[3 * i + 0] * 256.0f;
    float ys = V[3 * i + 1] * 256.0f;
    float zs = V[3 * i + 2] * 256.0f;
    float val = N[3 * i + d];
    int ix0 = (int)floorf(xs), iy0 = (int)floorf(ys), iz0 = (int)floorf(zs);
    float fx = xs - (float)ix0, fy = ys - (float)iy0, fz = zs - (float)iz0;
    int ix1 = (ix0 + 1) & 255, iy1 = (iy0 + 1) & 255, iz1 = (iz0 + 1) & 255;
    #pragma unroll
    for (int c = 0; c < 8; c++) {
        int bx = (c >> 2) & 1, by = (c >> 1) & 1, bz = c & 1;
        int ix = bx ? ix1 : ix0, iy = by ? iy1 : iy0, iz = bz ? iz1 : iz0;
        float w = (bx ? fx : 1.0f - fx) * (by ? fy : 1.0f - fy) * (bz ? fz : 1.0f - fz);
        atomicAdd(&R[(((size_t)ix << 8) + (size_t)iy) * 256 + (size_t)iz], w * val);
    }
}

// ---- forward rfft along z. Block: 16 (x,y)-lines. C layout [x][y][k], row khp ----
__global__ void k_rfft_z(const float* __restrict__ R, float2* __restrict__ C, int khp) {
    __shared__ float RE[16 * 257];
    __shared__ float IM[16 * 257];
    int x = blockIdx.x, y0 = blockIdx.y * 16, tid = threadIdx.x;
    #pragma unroll
    for (int l = 0; l < 16; l++) {
        float v = R[(((size_t)x << 8) + (y0 + l)) * 256 + tid];
        RE[l * 257 + rev4(tid)] = v;
        IM[l * 257 + rev4(tid)] = 0.0f;
    }
    fft256x16(RE, IM, tid, -1.0f);
    #pragma unroll
    for (int l = 0; l < 16; l++) {
        if (tid < KH) {
            C[(((size_t)x << 8) + (y0 + l)) * khp + tid] =
                make_float2(RE[l * 257 + tid], IM[l * 257 + tid]);
        }
    }
}

// ---- complex FFT along y, in place. Block: 16 k-columns at fixed x. ----
__global__ void k_fft_y(float2* __restrict__ C, int khp, float sign) {
    __shared__ float RE[16 * 257];
    __shared__ float IM[16 * 257];
    int x = blockIdx.x, k0 = blockIdx.y * 16, tid = threadIdx.x;
    int kl = tid & 15, k = k0 + kl;
    bool valid = (k < KH);
    float2* base = C + (size_t)x * 256 * khp + k;
    #pragma unroll
    for (int it = 0; it < 16; it++) {
        int y = (tid >> 4) + it * 16;
        float2 v = valid ? base[(size_t)y * khp] : make_float2(0.0f, 0.0f);
        RE[kl * 257 + rev4(y)] = v.x;
        IM[kl * 257 + rev4(y)] = v.y;
    }
    fft256x16(RE, IM, tid, sign);
    #pragma unroll
    for (int it = 0; it < 16; it++) {
        int y = (tid >> 4) + it * 16;
        if (valid) base[(size_t)y * khp] = make_float2(RE[kl * 257 + y], IM[kl * 257 + y]);
    }
}

// ---- forward FFT along x + spectral MAC into Acc; mode2 fuses inverse-x ----
__global__ void k_fft_x_acc(const float2* __restrict__ C, float2* __restrict__ Acc,
                            int khp, int mode, int d) {
    __shared__ float RE[16 * 257];
    __shared__ float IM[16 * 257];
    int y = blockIdx.x, k0 = blockIdx.y * 16, tid = threadIdx.x;
    int kl = tid & 15, k = k0 + kl;
    bool valid = (k < KH);
    size_t plane = (size_t)256 * khp;
    const float2* base = C + (size_t)y * khp + k;
    #pragma unroll
    for (int it = 0; it < 16; it++) {
        int n = (tid >> 4) + it * 16;
        float2 v = valid ? base[(size_t)n * plane] : make_float2(0.0f, 0.0f);
        RE[kl * 257 + rev4(n)] = v.x;
        IM[kl * 257 + rev4(n)] = v.y;
    }
    fft256x16(RE, IM, tid, -1.0f);
    float2* abase = Acc + (size_t)y * khp + k;
    float fy = (y < 128) ? (float)y : (float)(y - 256);
    float fz = (float)k;
    float vr[16], vi[16];
    #pragma unroll
    for (int it = 0; it < 16; it++) {
        int n = (tid >> 4) + it * 16;
        float fx = (n < 128) ? (float)n : (float)(n - 256);
        float f2 = fx * fx + fy * fy + fz * fz;
        float G = __expf(-0.0030517578125f * f2);          // exp(-0.5*(2*SIG*|f|/256)^2)
        float fd = (d == 0) ? fx : ((d == 1) ? fy : fz);
        float s = G * (6.283185307179586f * fd) / (1e-6f - 39.47841760435743f * f2);
        float xr = RE[kl * 257 + n], xi = IM[kl * 257 + n];
        float cr = s * xi, ci = -s * xr;                   // (-i*s)*v
        if (mode >= 1) {
            float2 old = valid ? abase[(size_t)n * plane] : make_float2(0.0f, 0.0f);
            cr += old.x; ci += old.y;
        }
        if (mode == 2) { vr[it] = cr; vi[it] = ci; }
        else if (valid) abase[(size_t)n * plane] = make_float2(cr, ci);
    }
    if (mode == 2) {
        __syncthreads();
        #pragma unroll
        for (int it = 0; it < 16; it++) {
            int n = (tid >> 4) + it * 16;
            RE[kl * 257 + rev4(n)] = vr[it];
            IM[kl * 257 + rev4(n)] = vi[it];
        }
        fft256x16(RE, IM, tid, 1.0f);
        #pragma unroll
        for (int it = 0; it < 16; it++) {
            int n = (tid >> 4) + it * 16;
            if (valid) abase[(size_t)n * plane] =
                make_float2(RE[kl * 257 + n], IM[kl * 257 + n]);
        }
    }
}

// ---- inverse rfft along z with Hermitian extension; 1/256^3 scale ----
__global__ void k_irfft_z(const float2* __restrict__ A, float* __restrict__ out, int khp) {
    __shared__ float RE[16 * 257];
    __shared__ float IM[16 * 257];
    int x = blockIdx.x, y0 = blockIdx.y * 16, tid = threadIdx.x;
    #pragma unroll
    for (int l = 0; l < 16; l++) {
        const float2* src = A + (((size_t)x << 8) + (y0 + l)) * khp;
        int n = tid;
        int k = (n <= 128) ? n : 256 - n;
        float2 v = src[k];
        RE[l * 257 + rev4(n)] = v.x;
        IM[l * 257 + rev4(n)] = (n <= 128) ? v.y : -v.y;
    }
    fft256x16(RE, IM, tid, 1.0f);
    const float sc = 1.0f / 16777216.0f;
    #pragma unroll
    for (int l = 0; l < 16; l++) {
        out[(((size_t)x << 8) + (y0 + l)) * 256 + tid] = RE[l * 257 + tid] * sc;
    }
}

// ---- trilinear interp of phi at points, sum-reduce into S ----
__global__ void k_interp_sum(const float* __restrict__ phi, const float* __restrict__ V,
                             float* __restrict__ S) {
    int i = blockIdx.x * blockDim.x + threadIdx.x;
    float acc = 0.0f;
    if (i < NPTS) {
        float xs = V[3 * i + 0] * 256.0f;
        float ys = V[3 * i + 1] * 256.0f;
        float zs = V[3 * i + 2] * 256.0f;
        int ix0 = (int)floorf(xs), iy0 = (int)floorf(ys), iz0 = (int)floorf(zs);
        float fx = xs - (float)ix0, fy = ys - (float)iy0, fz = zs - (float)iz0;
        int ix1 = (ix0 + 1) & 255, iy1 = (iy0 + 1) & 255, iz1 = (iz0 + 1) & 255;
        #pragma unroll
        for (int c = 0; c < 8; c++) {
            int bx = (c >> 2) & 1, by = (c >> 1) & 1, bz = c & 1;
            int ix = bx ? ix1 : ix0, iy = by ? iy1 : iy0, iz = bz ? iz1 : iz0;
            float w = (bx ? fx : 1.0f - fx) * (by ? fy : 1.0f - fy) * (bz ? fz : 1.0f - fz);
            acc += w * phi[(((size_t)ix << 8) + (size_t)iy) * 256 + (size_t)iz];
        }
    }
    #pragma unroll
    for (int off = 32; off > 0; off >>= 1) acc += __shfl_down(acc, off, 64);
    if ((threadIdx.x & 63) == 0) atomicAdd(S, acc);
}

__global__ void k_scalars(const float* __restrict__ S, const float* __restrict__ phi,
                          float* __restrict__ sc_out) {
    float mean = S[0] * (1.0f / (float)NPTS);
    sc_out[0] = mean;
    sc_out[1] = 0.5f / fabsf(phi[0] - mean);
}

__global__ void k_scale(float* __restrict__ phi, const float* __restrict__ sc) {
    size_t i = (size_t)blockIdx.x * blockDim.x + threadIdx.x;
    float mean = sc[0], inv = sc[1];
    float4* p = (float4*)phi;
    float4 v = p[i];
    v.x = -(v.x - mean) * inv;
    v.y = -(v.y - mean) * inv;
    v.z = -(v.z - mean) * inv;
    v.w = -(v.w - mean) * inv;
    p[i] = v;
}

extern "C" void kernel_launch(void* const* d_in, const int* in_sizes, int n_in,
                              void* d_out, int out_size, void* d_ws, size_t ws_size,
                              hipStream_t stream) {
    const float* V = (const float*)d_in[0];
    const float* N = (const float*)d_in[1];
    float* out = (float*)d_out;

    const size_t R_BYTES = 256ull * 256 * 256 * 4;            // 64 MiB
    const size_t C129 = 256ull * 256 * 129 * 8;
    const size_t C144 = 256ull * 256 * 144 * 8;               // aligned rows
    // sort buffers: cnt[NKEY], off[NKEY+1], cnt2[NKEY], idx[NPTS]
    const size_t SB_CNT  = ((NKEY * 4 + 255) / 256) * 256;
    const size_t SB_OFF  = (((NKEY + 1) * 4 + 255) / 256) * 256;
    const size_t SB_IDX  = ((NPTS * 4 + 255) / 256) * 256;
    const size_t SORT_BYTES = SB_CNT * 2 + SB_OFF + SB_IDX;

    int khp; size_t cbytes; int use_sort;
    if      (ws_size >= R_BYTES + 2 * C144 + 256 + SORT_BYTES) { khp = 144; cbytes = C144; use_sort = 1; }
    else if (ws_size >= R_BYTES + 2 * C129 + 256 + SORT_BYTES) { khp = 129; cbytes = C129; use_sort = 1; }
    else if (ws_size >= R_BYTES + 2 * C144 + 256)              { khp = 144; cbytes = C144; use_sort = 0; }
    else if (ws_size >= R_BYTES + 2 * C129 + 256)              { khp = 129; cbytes = C129; use_sort = 0; }
    else return;

    char* ws = (char*)d_ws;
    float*  R   = (float*)ws;
    float2* C   = (float2*)(ws + R_BYTES);
    float2* Acc = (float2*)(ws + R_BYTES + cbytes);
    float*  sc  = (float*)(ws + R_BYTES + 2 * cbytes);        // [0]=S, [1]=mean, [2]=inv
    char* sb = ws + R_BYTES + 2 * cbytes + 256;
    int* cnt  = (int*)sb;
    int* off  = (int*)(sb + SB_CNT);
    int* cnt2 = (int*)(sb + SB_CNT + SB_OFF);
    int* idx  = (int*)(sb + SB_CNT + SB_OFF + SB_CNT);

    hipMemsetAsync(sc, 0, 16, stream);

    dim3 b256(256);
    dim3 g_z(256, 16);    // 16-line tiles of (x, y0..y0+15)
    dim3 g_t(256, 9);     // 16-k tiles (9 tiles cover up to 144)
    dim3 g_pts((NPTS + 255) / 256);
    dim3 g_rast(16, 32, 32);   // cz, cy, cx

    if (use_sort) {
        hipMemsetAsync(cnt, 0, NKEY * 4, stream);
        k_hist<<<g_pts, b256, 0, stream>>>(V, cnt);
        k_scan<<<1, b256, 0, stream>>>(cnt, off, cnt2);
        k_scatter<<<g_pts, b256, 0, stream>>>(V, cnt2, idx);
    }

    for (int d = 0; d < 3; d++) {
        if (use_sort) {
            k_rastg<<<g_rast, b256, 0, stream>>>(idx, off, V, N, R, d);
        } else {
            hipMemsetAsync(R, 0, R_BYTES, stream);
            k_rasterize<<<g_pts, b256, 0, stream>>>(V, N, R, d);
        }
        k_rfft_z<<<g_z, b256, 0, stream>>>(R, C, khp);
        k_fft_y<<<g_t, b256, 0, stream>>>(C, khp, -1.0f);
        k_fft_x_acc<<<g_t, b256, 0, stream>>>(C, Acc, khp, d, d);  // mode = d
    }

    k_fft_y<<<g_t, b256, 0, stream>>>(Acc, khp, 1.0f);    // inverse y
    k_irfft_z<<<g_z, b256, 0, stream>>>(Acc, out, khp);   // inverse z + scale

    k_interp_sum<<<g_pts, b256, 0, stream>>>(out, V, sc);
    k_scalars<<<1, 1, 0, stream>>>(sc, out, sc + 1);
    k_scale<<<16777216 / 4 / 256, 256, 0, stream>>>(out, sc + 1);
}